// Round 8
// baseline (150.026 us; speedup 1.0000x reference)
//
#include <hip/hip_runtime.h>
#include <hip/hip_bf16.h>

#define B_ 64
#define C_ 512
#define HW_ 1024
#define R_ 32
#define NCHUNK 4
#define CPB 128   // channels per chunk
#define Q_ 4      // pixel quarters
#define PPB 256   // pixels per block
#define PFD 4     // x prefetch depth (channels ahead)

// ---------------------------------------------------------------------------
// 8-lane group sum on the VALU pipe (DPP), no LDS traffic.
// xor1 = quad_perm[1,0,3,2] (0xB1), xor2 = quad_perm[2,3,0,1] (0x4E),
// then row_half_mirror (0x141) folds the two quads of each 8-lane group.
// ---------------------------------------------------------------------------
__device__ __forceinline__ float dpp_fold8(float s) {
    int y;
    y = __builtin_amdgcn_update_dpp(0, __float_as_int(s), 0xB1, 0xF, 0xF, true);
    s += __int_as_float(y);
    y = __builtin_amdgcn_update_dpp(0, __float_as_int(s), 0x4E, 0xF, 0xF, true);
    s += __int_as_float(y);
    y = __builtin_amdgcn_update_dpp(0, __float_as_int(s), 0x141, 0xF, 0xF, true);
    s += __int_as_float(y);
    return s;
}

// ---------------------------------------------------------------------------
// A0: transpose w_eig (R,C) -> wt (C,R): per-channel rows of 32 contiguous,
// so k_proj's uniform weight reads become s_load streams.
// ---------------------------------------------------------------------------
__global__ void k_transpose_w(const float* __restrict__ w_eig,
                              float* __restrict__ wt) {
    int idx = blockIdx.x * 1024 + threadIdx.x;   // grid 16 x 1024 = 16384
    int r = idx >> 9;
    int c = idx & 511;
    wt[c * R_ + r] = w_eig[idx];                 // w_eig[r*512 + c]
}

// ---------------------------------------------------------------------------
// A: one pass over x. Block = (b, c-chunk, pixel-quarter); 256 threads,
// 1 pixel/thread; grid 1024. Weights read at THREAD-UNIFORM global
// addresses -> scalar loads into SGPRs. Pooled partial via DPP fold.
// Depth-4 rotating x prefetch keeps ~12-16 KB/CU in flight (HBM latency
// ~900 cy needs ~9.4 KB/CU at our per-CU BW share).
// ---------------------------------------------------------------------------
__global__ __launch_bounds__(256, 4) void k_proj(
    const float* __restrict__ x, const float* __restrict__ wt,
    const float* __restrict__ w_sp,
    __hip_bfloat16* __restrict__ featp, __hip_bfloat16* __restrict__ sppb,
    float* __restrict__ pooledp)
{
    const int t   = threadIdx.x;         // 0..255
    const int blk = blockIdx.x;          // ((b*4)+ch)*4 + q
    const int q   = blk & 3;
    const int ch  = (blk >> 2) & 3;
    const int b   = blk >> 4;
    const int c0  = ch * CPB;
    const int n   = q * PPB + t;         // this thread's pixel

    __shared__ float plds[CPB][33];      // 16.9 KB pooled partials
    __shared__ float red2[CPB][2];       // 1 KB

    const float* wch = wt + (size_t)c0 * R_;   // uniform base

    float acc[R_];
#pragma unroll
    for (int r = 0; r < R_; ++r) acc[r] = 0.f;
    float sp = 0.f;

    const float* xb = x + ((size_t)(b * C_ + c0)) * HW_ + n;

    // depth-4 rotating prefetch buffer (indices static under unroll 4)
    float xq[PFD];
#pragma unroll
    for (int d = 0; d < PFD; ++d) xq[d] = xb[(size_t)d * HW_];

#pragma unroll 4
    for (int j = 0; j < CPB; ++j) {
        float xv = xq[j & (PFD - 1)];
        // prefetch channel j+4 into the slot just consumed (wraps harmlessly)
        xq[j & (PFD - 1)] = xb[(size_t)((j + PFD) & (CPB - 1)) * HW_];

        // 32 weights at a uniform address -> s_load into SGPRs
        const float4* wr = (const float4*)(wch + j * R_);
#pragma unroll
        for (int k = 0; k < 8; ++k) {
            float4 w = wr[k];
            acc[4 * k + 0] = fmaf(w.x, xv, acc[4 * k + 0]);
            acc[4 * k + 1] = fmaf(w.y, xv, acc[4 * k + 1]);
            acc[4 * k + 2] = fmaf(w.z, xv, acc[4 * k + 2]);
            acc[4 * k + 3] = fmaf(w.w, xv, acc[4 * k + 3]);
        }

        sp = fmaf(w_sp[c0 + j], xv, sp);   // uniform -> s_load

        // pooled partial: DPP 8-lane fold (VALU), one store per 8 lanes
        float s = dpp_fold8(xv);
        if ((t & 7) == 0) plds[j][t >> 3] = s;   // 32 partials per channel
    }
    __syncthreads();

    // pooled final reduce: thread t -> channel t>>1, half t&1 (16 values)
    {
        const int j = t >> 1, h = t & 1;
        float s = 0.f;
#pragma unroll
        for (int i = 0; i < 16; ++i) s += plds[j][h * 16 + i];
        red2[j][h] = s;
    }
    __syncthreads();
    if (t < CPB)
        pooledp[(((size_t)q * B_ + b) * C_) + c0 + t] = red2[t][0] + red2[t][1];

    sppb[((size_t)(ch * B_ + b)) * HW_ + n] = __float2bfloat16(sp);

    // featp bf16, layout [(ch*B+b)*HW + n][r] -> 64B per thread
    __hip_bfloat16* fb = featp + ((size_t)((ch * B_ + b) * HW_ + n)) * R_;
    union { __hip_bfloat16 h[R_]; uint4 qv[4]; } u;
#pragma unroll
    for (int r = 0; r < R_; ++r) u.h[r] = __float2bfloat16(acc[r]);
#pragma unroll
    for (int k = 0; k < 4; ++k) ((uint4*)fb)[k] = u.qv[k];
}

// ---------------------------------------------------------------------------
// B: per-batch block (64 blocks, 1024 threads = one per pixel).
// Power-iteration reduction: DPP 8-lane fold -> 128 f32 partials per r,
// packed float2 stores, then 2-stage combine. (Unchanged from passing r7.)
// ---------------------------------------------------------------------------
__global__ __launch_bounds__(1024) void k_eigen(
    const __hip_bfloat16* __restrict__ featp,
    const __hip_bfloat16* __restrict__ sppb,
    const float* __restrict__ pooledp,
    const float* __restrict__ w_eig, const float* __restrict__ w_fc1,
    const float* __restrict__ b_fc1, const float* __restrict__ w_fc2,
    const float* __restrict__ b_fc2, const float* __restrict__ b_sp,
    const float* __restrict__ v0,
    float* __restrict__ ca_out, float* __restrict__ att_out)
{
    const int b    = blockIdx.x;
    const int t    = threadIdx.x;
    const int lane = t & 63;
    const int wave = t >> 6;

    __shared__ float pooledm[C_];
    __shared__ float meanv[R_], t1[R_], vv[R_], wred[R_];
    __shared__ float plds2[R_ / 2][128][2];   // 16 KB: [r>>1][partial][r&1]
    __shared__ float redmn[16], redmx[16], scal[2];

    // ---- pooled mean: combine the 4 pixel-quarter partials
    if (t < C_) {
        float s = 0.f;
#pragma unroll
        for (int qq = 0; qq < Q_; ++qq)
            s += pooledp[((size_t)qq * B_ + b) * C_ + t];
        pooledm[t] = s * (1.f / 1024.f);
    }
    __syncthreads();

    // ---- mean[r] = (w_eig @ pooled_mean)[r]; t1[r] = relu(fc1 @ pm + b)
    if (t < 512) {
        const int r = t >> 4, k = t & 15;
        float pm = 0.f, pf = 0.f;
        for (int c = k; c < C_; c += 16) {
            float p = pooledm[c];
            pm = fmaf(w_eig[r * C_ + c], p, pm);
            pf = fmaf(w_fc1[r * C_ + c], p, pf);
        }
#pragma unroll
        for (int m = 8; m > 0; m >>= 1) {
            pm += __shfl_xor(pm, m, 64);
            pf += __shfl_xor(pf, m, 64);
        }
        if (k == 0) { meanv[r] = pm; t1[r] = fmaxf(pf + b_fc1[r], 0.f); }
    }
    __syncthreads();

    // ---- channel attention ca[c] = sigmoid(w_fc2[c,:] @ t1 + b_fc2[c])
    if (t < C_) {
        float s = b_fc2[t];
        const float4* w4 = (const float4*)(w_fc2 + (size_t)t * R_);
#pragma unroll
        for (int k = 0; k < 8; ++k) {
            float4 w = w4[k];
            s = fmaf(w.x, t1[4 * k + 0], s);
            s = fmaf(w.y, t1[4 * k + 1], s);
            s = fmaf(w.z, t1[4 * k + 2], s);
            s = fmaf(w.w, t1[4 * k + 3], s);
        }
        ca_out[b * C_ + t] = 1.f / (1.f + expf(-s));
    }

    // ---- build centered column F_c[:, t] in registers (b_eig cancels)
    float col[R_];
#pragma unroll
    for (int r = 0; r < R_; ++r) col[r] = -meanv[r];
    for (int ch = 0; ch < NCHUNK; ++ch) {
        union { __hip_bfloat16 h[R_]; uint4 qv[4]; } u;
        const uint4* src =
            (const uint4*)(featp + ((size_t)((ch * B_ + b) * HW_ + t)) * R_);
#pragma unroll
        for (int k = 0; k < 4; ++k) u.qv[k] = src[k];
#pragma unroll
        for (int r = 0; r < R_; ++r) col[r] += __bfloat162float(u.h[r]);
    }

    // ---- v = v0 / ||v0||
    if (t < 64) {
        float vl = (t < R_) ? v0[b * R_ + t] : 0.f;
        float sq = vl * vl;
#pragma unroll
        for (int m = 32; m > 0; m >>= 1) sq += __shfl_xor(sq, m, 64);
        if (t < R_) vv[t] = vl / sqrtf(sq);
    }
    __syncthreads();

    // ---- 5 power iterations: v <- normalize(F (F^T v)/1023 + 1e-5 v)
    for (int it = 0; it < 5; ++it) {
        float uacc = 0.f;
#pragma unroll
        for (int r = 0; r < R_; ++r) uacc = fmaf(col[r], vv[r], uacc);
        uacc *= (1.f / 1023.f);

        // stage 1: DPP 8-lane fold, packed float2 store (r pair)
#pragma unroll
        for (int g = 0; g < R_ / 2; ++g) {
            float s0 = dpp_fold8(col[2 * g + 0] * uacc);
            float s1 = dpp_fold8(col[2 * g + 1] * uacc);
            if ((t & 7) == 0) {
                plds2[g][t >> 3][0] = s0;
                plds2[g][t >> 3][1] = s1;
            }
        }
        __syncthreads();

        // stage 2: r = t>>5, i = t&31 sums its 4 partials, 5-level fold
        {
            const int r = t >> 5, i = t & 31;
            const int g = r >> 1, e = r & 1;
            float s = plds2[g][i][e] + plds2[g][i + 32][e] +
                      plds2[g][i + 64][e] + plds2[g][i + 96][e];
#pragma unroll
            for (int m = 16; m > 0; m >>= 1) s += __shfl_xor(s, m, 64);
            if (i == 0) wred[r] = s;
        }
        __syncthreads();

        if (t < 64) {
            float w = (t < R_) ? wred[t] + 1e-5f * vv[t] : 0.f;
            float sq = w * w;
#pragma unroll
            for (int m = 32; m > 0; m >>= 1) sq += __shfl_xor(sq, m, 64);
            if (t < R_) vv[t] = w / (sqrtf(sq) + 1e-10f);
        }
        __syncthreads();
    }

    // ---- att, min/max, eigen_att, spatial_att
    float a = 0.f;
#pragma unroll
    for (int r = 0; r < R_; ++r) a = fmaf(col[r], vv[r], a);

    float mn = a, mx = a;
#pragma unroll
    for (int m = 32; m > 0; m >>= 1) {
        mn = fminf(mn, __shfl_xor(mn, m, 64));
        mx = fmaxf(mx, __shfl_xor(mx, m, 64));
    }
    if (lane == 0) { redmn[wave] = mn; redmx[wave] = mx; }
    __syncthreads();
    if (t == 0) {
        float m1 = redmn[0], m2 = redmx[0];
        for (int w = 1; w < 16; ++w) {
            m1 = fminf(m1, redmn[w]);
            m2 = fmaxf(m2, redmx[w]);
        }
        scal[0] = m1; scal[1] = m2;
    }
    __syncthreads();

    const float amin  = scal[0];
    const float denom = (scal[1] - scal[0]) + 1e-10f;
    float eig = 1.f / (1.f + expf(-((a - amin) / denom)));

    float ssum = b_sp[0];
#pragma unroll
    for (int ch = 0; ch < NCHUNK; ++ch)
        ssum += __bfloat162float(sppb[((size_t)(ch * B_ + b)) * HW_ + t]);
    float spsig = 1.f / (1.f + expf(-ssum));

    att_out[b * HW_ + t] = eig * spsig;
}

// ---------------------------------------------------------------------------
// C: out = x * (1 + ca[b,c] * att_all[b,n]), float4 streaming.
// ---------------------------------------------------------------------------
__global__ __launch_bounds__(256) void k_final(
    const float* __restrict__ x, const float* __restrict__ ca,
    const float* __restrict__ att, float* __restrict__ out)
{
    const int t   = threadIdx.x;
    const int blk = blockIdx.x;          // b*C_ + c
    const int b   = blk >> 9;
    const float cav  = ca[blk];
    const size_t base = (size_t)blk * HW_;

    float4 xv = ((const float4*)(x + base))[t];
    float4 av = ((const float4*)(att + (size_t)b * HW_))[t];
    float4 o;
    o.x = fmaf(xv.x * cav, av.x, xv.x);
    o.y = fmaf(xv.y * cav, av.y, xv.y);
    o.z = fmaf(xv.z * cav, av.z, xv.z);
    o.w = fmaf(xv.w * cav, av.w, xv.w);
    ((float4*)(out + base))[t] = o;
}

// ---------------------------------------------------------------------------
extern "C" void kernel_launch(void* const* d_in, const int* in_sizes, int n_in,
                              void* d_out, int out_size, void* d_ws, size_t ws_size,
                              hipStream_t stream) {
    const float* x     = (const float*)d_in[0];
    const float* w_fc1 = (const float*)d_in[1];
    const float* b_fc1 = (const float*)d_in[2];
    const float* w_fc2 = (const float*)d_in[3];
    const float* b_fc2 = (const float*)d_in[4];
    const float* w_eig = (const float*)d_in[5];
    // d_in[6] = b_eig: cancels under mean-centering; unused.
    const float* w_sp  = (const float*)d_in[7];
    const float* b_sp  = (const float*)d_in[8];
    const float* v0    = (const float*)d_in[9];
    float* out = (float*)d_out;

    // workspace layout (bytes); total 18,284,544 (< proven 18,415,616)
    char* ws = (char*)d_ws;
    __hip_bfloat16* featp = (__hip_bfloat16*)ws;             // 16,777,216: 4*64*1024*32 bf16
    __hip_bfloat16* sppb  = (__hip_bfloat16*)(ws + 16777216);//    524,288: 4*64*1024 bf16
    float* pooledp = (float*)(ws + 17301504);                //    524,288: 4*64*512 f32
    float* ca      = (float*)(ws + 17825792);                //    131,072: 64*512 f32
    float* att     = (float*)(ws + 17956864);                //    262,144: 64*1024 f32
    float* wt      = (float*)(ws + 18219008);                //     65,536: 512*32 f32

    k_transpose_w<<<16, 1024, 0, stream>>>(w_eig, wt);
    k_proj<<<B_ * NCHUNK * Q_, 256, 0, stream>>>(x, wt, w_sp,
                                                 featp, sppb, pooledp);
    k_eigen<<<B_, 1024, 0, stream>>>(featp, sppb, pooledp, w_eig, w_fc1, b_fc1,
                                     w_fc2, b_fc2, b_sp, v0, ca, att);
    k_final<<<B_ * C_, 256, 0, stream>>>(x, ca, att, out);
}

// Round 9
// 141.735 us; speedup vs baseline: 1.0585x; 1.0585x over previous
//
#include <hip/hip_runtime.h>
#include <hip/hip_bf16.h>

#define B_ 64
#define C_ 512
#define HW_ 1024
#define R_ 32
#define NCHUNK 4
#define CPB 128   // channels per chunk
#define Q_ 4      // pixel quarters
#define PPB 256   // pixels per block

// ---------------------------------------------------------------------------
// 8-lane group sum on the VALU pipe (DPP), no LDS traffic.
// xor1 = quad_perm[1,0,3,2] (0xB1), xor2 = quad_perm[2,3,0,1] (0x4E),
// then row_half_mirror (0x141) folds the two quads of each 8-lane group.
// ---------------------------------------------------------------------------
__device__ __forceinline__ float dpp_fold8(float s) {
    int y;
    y = __builtin_amdgcn_update_dpp(0, __float_as_int(s), 0xB1, 0xF, 0xF, true);
    s += __int_as_float(y);
    y = __builtin_amdgcn_update_dpp(0, __float_as_int(s), 0x4E, 0xF, 0xF, true);
    s += __int_as_float(y);
    y = __builtin_amdgcn_update_dpp(0, __float_as_int(s), 0x141, 0xF, 0xF, true);
    s += __int_as_float(y);
    return s;
}

// ---------------------------------------------------------------------------
// A0: transpose w_eig (R,C) -> wt (C,R): per-channel rows of 32 contiguous,
// so k_proj's uniform weight reads become s_load streams.
// ---------------------------------------------------------------------------
__global__ void k_transpose_w(const float* __restrict__ w_eig,
                              float* __restrict__ wt) {
    int idx = blockIdx.x * 1024 + threadIdx.x;   // grid 16 x 1024 = 16384
    int r = idx >> 9;
    int c = idx & 511;
    wt[c * R_ + r] = w_eig[idx];                 // w_eig[r*512 + c]
}

// ---------------------------------------------------------------------------
// A: one pass over x. Block = (b, c-chunk, pixel-quarter); 256 threads,
// 1 pixel/thread; grid 1024 (4 blocks/CU, 16 waves/CU). Weights read at
// THREAD-UNIFORM addresses -> SGPR scalar loads. Pooled partial via DPP.
// 4-deep prefetch with NAMED registers (x0..x3 / n0..n3) — fully static
// register references; the round-8 rotating-buffer pragma version made the
// compiler demote acc[] to AGPRs (VGPR_Count 28, 3x VALU issue).
// ---------------------------------------------------------------------------
#define PROJ_BODY(J, XV)                                               \
    {                                                                  \
        const float4* wr_ = (const float4*)(wch + (J) * R_);           \
        _Pragma("unroll")                                              \
        for (int k = 0; k < 8; ++k) {                                  \
            float4 w = wr_[k];                                         \
            acc[4 * k + 0] = fmaf(w.x, (XV), acc[4 * k + 0]);          \
            acc[4 * k + 1] = fmaf(w.y, (XV), acc[4 * k + 1]);          \
            acc[4 * k + 2] = fmaf(w.z, (XV), acc[4 * k + 2]);          \
            acc[4 * k + 3] = fmaf(w.w, (XV), acc[4 * k + 3]);          \
        }                                                              \
        sp = fmaf(w_sp[c0 + (J)], (XV), sp);                           \
        float s_ = dpp_fold8(XV);                                      \
        if ((t & 7) == 0) plds[(J)][t >> 3] = s_;                      \
    }

__global__ __launch_bounds__(256, 4) void k_proj(
    const float* __restrict__ x, const float* __restrict__ wt,
    const float* __restrict__ w_sp,
    __hip_bfloat16* __restrict__ featp, __hip_bfloat16* __restrict__ sppb,
    float* __restrict__ pooledp)
{
    const int t   = threadIdx.x;         // 0..255
    const int blk = blockIdx.x;          // ((b*4)+ch)*4 + q
    const int q   = blk & 3;
    const int ch  = (blk >> 2) & 3;
    const int b   = blk >> 4;
    const int c0  = ch * CPB;
    const int n   = q * PPB + t;         // this thread's pixel

    __shared__ float plds[CPB][33];      // 16.9 KB pooled partials
    __shared__ float red2[CPB][2];       // 1 KB

    const float* wch = wt + (size_t)c0 * R_;   // uniform base

    float acc[R_];
#pragma unroll
    for (int r = 0; r < R_; ++r) acc[r] = 0.f;
    float sp = 0.f;

    const float* xb = x + ((size_t)(b * C_ + c0)) * HW_ + n;

    // 4-deep prefetch, named registers only
    float x0 = xb[0 * HW_];
    float x1 = xb[1 * HW_];
    float x2 = xb[2 * HW_];
    float x3 = xb[3 * HW_];

    for (int j = 0; j < CPB; j += 4) {
        // issue next 4 loads (wraps harmlessly on the final iteration)
        float n0 = xb[(size_t)((j + 4) & (CPB - 1)) * HW_];
        float n1 = xb[(size_t)((j + 5) & (CPB - 1)) * HW_];
        float n2 = xb[(size_t)((j + 6) & (CPB - 1)) * HW_];
        float n3 = xb[(size_t)((j + 7) & (CPB - 1)) * HW_];

        PROJ_BODY(j + 0, x0)
        PROJ_BODY(j + 1, x1)
        PROJ_BODY(j + 2, x2)
        PROJ_BODY(j + 3, x3)

        x0 = n0; x1 = n1; x2 = n2; x3 = n3;
    }
    __syncthreads();

    // pooled final reduce: thread t -> channel t>>1, half t&1 (16 values)
    {
        const int j = t >> 1, h = t & 1;
        float s = 0.f;
#pragma unroll
        for (int i = 0; i < 16; ++i) s += plds[j][h * 16 + i];
        red2[j][h] = s;
    }
    __syncthreads();
    if (t < CPB)
        pooledp[(((size_t)q * B_ + b) * C_) + c0 + t] = red2[t][0] + red2[t][1];

    sppb[((size_t)(ch * B_ + b)) * HW_ + n] = __float2bfloat16(sp);

    // featp bf16, layout [(ch*B+b)*HW + n][r] -> 64B per thread
    __hip_bfloat16* fb = featp + ((size_t)((ch * B_ + b) * HW_ + n)) * R_;
    union { __hip_bfloat16 h[R_]; uint4 qv[4]; } u;
#pragma unroll
    for (int r = 0; r < R_; ++r) u.h[r] = __float2bfloat16(acc[r]);
#pragma unroll
    for (int k = 0; k < 4; ++k) ((uint4*)fb)[k] = u.qv[k];
}

// ---------------------------------------------------------------------------
// B: per-batch block (64 blocks, 1024 threads = one per pixel).
// Power-iteration reduction: DPP 8-lane fold -> 128 f32 partials per r,
// packed float2 stores, then 2-stage combine. (Unchanged, known-good.)
// ---------------------------------------------------------------------------
__global__ __launch_bounds__(1024) void k_eigen(
    const __hip_bfloat16* __restrict__ featp,
    const __hip_bfloat16* __restrict__ sppb,
    const float* __restrict__ pooledp,
    const float* __restrict__ w_eig, const float* __restrict__ w_fc1,
    const float* __restrict__ b_fc1, const float* __restrict__ w_fc2,
    const float* __restrict__ b_fc2, const float* __restrict__ b_sp,
    const float* __restrict__ v0,
    float* __restrict__ ca_out, float* __restrict__ att_out)
{
    const int b    = blockIdx.x;
    const int t    = threadIdx.x;
    const int lane = t & 63;
    const int wave = t >> 6;

    __shared__ float pooledm[C_];
    __shared__ float meanv[R_], t1[R_], vv[R_], wred[R_];
    __shared__ float plds2[R_ / 2][128][2];   // 16 KB: [r>>1][partial][r&1]
    __shared__ float redmn[16], redmx[16], scal[2];

    // ---- pooled mean: combine the 4 pixel-quarter partials
    if (t < C_) {
        float s = 0.f;
#pragma unroll
        for (int qq = 0; qq < Q_; ++qq)
            s += pooledp[((size_t)qq * B_ + b) * C_ + t];
        pooledm[t] = s * (1.f / 1024.f);
    }
    __syncthreads();

    // ---- mean[r] = (w_eig @ pooled_mean)[r]; t1[r] = relu(fc1 @ pm + b)
    if (t < 512) {
        const int r = t >> 4, k = t & 15;
        float pm = 0.f, pf = 0.f;
        for (int c = k; c < C_; c += 16) {
            float p = pooledm[c];
            pm = fmaf(w_eig[r * C_ + c], p, pm);
            pf = fmaf(w_fc1[r * C_ + c], p, pf);
        }
#pragma unroll
        for (int m = 8; m > 0; m >>= 1) {
            pm += __shfl_xor(pm, m, 64);
            pf += __shfl_xor(pf, m, 64);
        }
        if (k == 0) { meanv[r] = pm; t1[r] = fmaxf(pf + b_fc1[r], 0.f); }
    }
    __syncthreads();

    // ---- channel attention ca[c] = sigmoid(w_fc2[c,:] @ t1 + b_fc2[c])
    if (t < C_) {
        float s = b_fc2[t];
        const float4* w4 = (const float4*)(w_fc2 + (size_t)t * R_);
#pragma unroll
        for (int k = 0; k < 8; ++k) {
            float4 w = w4[k];
            s = fmaf(w.x, t1[4 * k + 0], s);
            s = fmaf(w.y, t1[4 * k + 1], s);
            s = fmaf(w.z, t1[4 * k + 2], s);
            s = fmaf(w.w, t1[4 * k + 3], s);
        }
        ca_out[b * C_ + t] = 1.f / (1.f + expf(-s));
    }

    // ---- build centered column F_c[:, t] in registers (b_eig cancels)
    float col[R_];
#pragma unroll
    for (int r = 0; r < R_; ++r) col[r] = -meanv[r];
    for (int ch = 0; ch < NCHUNK; ++ch) {
        union { __hip_bfloat16 h[R_]; uint4 qv[4]; } u;
        const uint4* src =
            (const uint4*)(featp + ((size_t)((ch * B_ + b) * HW_ + t)) * R_);
#pragma unroll
        for (int k = 0; k < 4; ++k) u.qv[k] = src[k];
#pragma unroll
        for (int r = 0; r < R_; ++r) col[r] += __bfloat162float(u.h[r]);
    }

    // ---- v = v0 / ||v0||
    if (t < 64) {
        float vl = (t < R_) ? v0[b * R_ + t] : 0.f;
        float sq = vl * vl;
#pragma unroll
        for (int m = 32; m > 0; m >>= 1) sq += __shfl_xor(sq, m, 64);
        if (t < R_) vv[t] = vl / sqrtf(sq);
    }
    __syncthreads();

    // ---- 5 power iterations: v <- normalize(F (F^T v)/1023 + 1e-5 v)
    for (int it = 0; it < 5; ++it) {
        float uacc = 0.f;
#pragma unroll
        for (int r = 0; r < R_; ++r) uacc = fmaf(col[r], vv[r], uacc);
        uacc *= (1.f / 1023.f);

        // stage 1: DPP 8-lane fold, packed float2 store (r pair)
#pragma unroll
        for (int g = 0; g < R_ / 2; ++g) {
            float s0 = dpp_fold8(col[2 * g + 0] * uacc);
            float s1 = dpp_fold8(col[2 * g + 1] * uacc);
            if ((t & 7) == 0) {
                plds2[g][t >> 3][0] = s0;
                plds2[g][t >> 3][1] = s1;
            }
        }
        __syncthreads();

        // stage 2: r = t>>5, i = t&31 sums its 4 partials, 5-level fold
        {
            const int r = t >> 5, i = t & 31;
            const int g = r >> 1, e = r & 1;
            float s = plds2[g][i][e] + plds2[g][i + 32][e] +
                      plds2[g][i + 64][e] + plds2[g][i + 96][e];
#pragma unroll
            for (int m = 16; m > 0; m >>= 1) s += __shfl_xor(s, m, 64);
            if (i == 0) wred[r] = s;
        }
        __syncthreads();

        if (t < 64) {
            float w = (t < R_) ? wred[t] + 1e-5f * vv[t] : 0.f;
            float sq = w * w;
#pragma unroll
            for (int m = 32; m > 0; m >>= 1) sq += __shfl_xor(sq, m, 64);
            if (t < R_) vv[t] = w / (sqrtf(sq) + 1e-10f);
        }
        __syncthreads();
    }

    // ---- att, min/max, eigen_att, spatial_att
    float a = 0.f;
#pragma unroll
    for (int r = 0; r < R_; ++r) a = fmaf(col[r], vv[r], a);

    float mn = a, mx = a;
#pragma unroll
    for (int m = 32; m > 0; m >>= 1) {
        mn = fminf(mn, __shfl_xor(mn, m, 64));
        mx = fmaxf(mx, __shfl_xor(mx, m, 64));
    }
    if (lane == 0) { redmn[wave] = mn; redmx[wave] = mx; }
    __syncthreads();
    if (t == 0) {
        float m1 = redmn[0], m2 = redmx[0];
        for (int w = 1; w < 16; ++w) {
            m1 = fminf(m1, redmn[w]);
            m2 = fmaxf(m2, redmx[w]);
        }
        scal[0] = m1; scal[1] = m2;
    }
    __syncthreads();

    const float amin  = scal[0];
    const float denom = (scal[1] - scal[0]) + 1e-10f;
    float eig = 1.f / (1.f + expf(-((a - amin) / denom)));

    float ssum = b_sp[0];
#pragma unroll
    for (int ch = 0; ch < NCHUNK; ++ch)
        ssum += __bfloat162float(sppb[((size_t)(ch * B_ + b)) * HW_ + t]);
    float spsig = 1.f / (1.f + expf(-ssum));

    att_out[b * HW_ + t] = eig * spsig;
}

// ---------------------------------------------------------------------------
// C: out = x * (1 + ca[b,c] * att_all[b,n]), float4 streaming.
// ---------------------------------------------------------------------------
__global__ __launch_bounds__(256) void k_final(
    const float* __restrict__ x, const float* __restrict__ ca,
    const float* __restrict__ att, float* __restrict__ out)
{
    const int t   = threadIdx.x;
    const int blk = blockIdx.x;          // b*C_ + c
    const int b   = blk >> 9;
    const float cav  = ca[blk];
    const size_t base = (size_t)blk * HW_;

    float4 xv = ((const float4*)(x + base))[t];
    float4 av = ((const float4*)(att + (size_t)b * HW_))[t];
    float4 o;
    o.x = fmaf(xv.x * cav, av.x, xv.x);
    o.y = fmaf(xv.y * cav, av.y, xv.y);
    o.z = fmaf(xv.z * cav, av.z, xv.z);
    o.w = fmaf(xv.w * cav, av.w, xv.w);
    ((float4*)(out + base))[t] = o;
}

// ---------------------------------------------------------------------------
extern "C" void kernel_launch(void* const* d_in, const int* in_sizes, int n_in,
                              void* d_out, int out_size, void* d_ws, size_t ws_size,
                              hipStream_t stream) {
    const float* x     = (const float*)d_in[0];
    const float* w_fc1 = (const float*)d_in[1];
    const float* b_fc1 = (const float*)d_in[2];
    const float* w_fc2 = (const float*)d_in[3];
    const float* b_fc2 = (const float*)d_in[4];
    const float* w_eig = (const float*)d_in[5];
    // d_in[6] = b_eig: cancels under mean-centering; unused.
    const float* w_sp  = (const float*)d_in[7];
    const float* b_sp  = (const float*)d_in[8];
    const float* v0    = (const float*)d_in[9];
    float* out = (float*)d_out;

    // workspace layout (bytes); total 18,284,544 (< proven 18,415,616)
    char* ws = (char*)d_ws;
    __hip_bfloat16* featp = (__hip_bfloat16*)ws;             // 16,777,216: 4*64*1024*32 bf16
    __hip_bfloat16* sppb  = (__hip_bfloat16*)(ws + 16777216);//    524,288: 4*64*1024 bf16
    float* pooledp = (float*)(ws + 17301504);                //    524,288: 4*64*512 f32
    float* ca      = (float*)(ws + 17825792);                //    131,072: 64*512 f32
    float* att     = (float*)(ws + 17956864);                //    262,144: 64*1024 f32
    float* wt      = (float*)(ws + 18219008);                //     65,536: 512*32 f32

    k_transpose_w<<<16, 1024, 0, stream>>>(w_eig, wt);
    k_proj<<<B_ * NCHUNK * Q_, 256, 0, stream>>>(x, wt, w_sp,
                                                 featp, sppb, pooledp);
    k_eigen<<<B_, 1024, 0, stream>>>(featp, sppb, pooledp, w_eig, w_fc1, b_fc1,
                                     w_fc2, b_fc2, b_sp, v0, ca, att);
    k_final<<<B_ * C_, 256, 0, stream>>>(x, ca, att, out);
}

// Round 10
// 94.667 us; speedup vs baseline: 1.5848x; 1.4972x over previous
//
#include <hip/hip_runtime.h>
#include <hip/hip_bf16.h>

#define B_ 64
#define C_ 512
#define HW_ 1024
#define R_ 32
#define NPXG 16   // pixel groups per batch (64 px each)

typedef __attribute__((ext_vector_type(8))) short bf16x8;
typedef __attribute__((ext_vector_type(4))) float f32x4;

union U8 { uint4 q; bf16x8 v; unsigned short s[8]; };

__device__ __forceinline__ unsigned short f2bf(float f) {
    __hip_bfloat16 h = __float2bfloat16(f);
    union { __hip_bfloat16 b; unsigned short u; } c; c.b = h; return c.u;
}

// 16-lane row sum on the VALU pipe: xor1 (quad 0xB1), xor2 (quad 0x4E),
// row_half_mirror (0x141), row_mirror (0x140). All lanes end with the sum.
__device__ __forceinline__ float dpp_fold16(float s) {
    int y;
    y = __builtin_amdgcn_update_dpp(0, __float_as_int(s), 0xB1, 0xF, 0xF, true);
    s += __int_as_float(y);
    y = __builtin_amdgcn_update_dpp(0, __float_as_int(s), 0x4E, 0xF, 0xF, true);
    s += __int_as_float(y);
    y = __builtin_amdgcn_update_dpp(0, __float_as_int(s), 0x141, 0xF, 0xF, true);
    s += __int_as_float(y);
    y = __builtin_amdgcn_update_dpp(0, __float_as_int(s), 0x140, 0xF, 0xF, true);
    s += __int_as_float(y);
    return s;
}

// ---------------------------------------------------------------------------
// P: pack A-operand fragments (bf16, fragment-ordered) for k_proj's MFMAs.
// slot 0/1: W rows 0-15 / 16-31.  slot 2: row0 = w_sp, rows 1-15 = 0.
// Fragment rule (A, 16x16x32): lane l holds A[m=l&15][k=8*(l>>4)+i], i=0..7.
// wfrag[slot*1024 + kstep*64 + lane] = uint4 of 8 bf16.
// ---------------------------------------------------------------------------
__global__ void k_prep(const float* __restrict__ w_eig,
                       const float* __restrict__ w_sp,
                       uint4* __restrict__ wfrag) {
    int idx   = blockIdx.x * 256 + threadIdx.x;   // grid 12 x 256 = 3072
    int lane  = idx & 63;
    int kstep = (idx >> 6) & 15;
    int slot  = idx >> 10;
    int m = lane & 15, g = lane >> 4;
    int cbase = kstep * 32 + 8 * g;

    U8 u;
    if (slot < 2) {
        int r = slot * 16 + m;
#pragma unroll
        for (int i = 0; i < 8; ++i) u.s[i] = f2bf(w_eig[r * C_ + cbase + i]);
    } else {
#pragma unroll
        for (int i = 0; i < 8; ++i)
            u.s[i] = (m == 0) ? f2bf(w_sp[cbase + i]) : (unsigned short)0;
    }
    wfrag[idx] = u.q;
}

// ---------------------------------------------------------------------------
// A: MFMA projection. Block = (b, pxgroup): 4 waves x 16 px = 64 px.
// Per wave: full K=512 in 16 steps; 3 MFMAs/step (feat r0-15, r16-31, w_sp).
// x loaded f32 (8 dwords/lane/step, ~8 outstanding -> BW-bound), cast bf16.
// pooled[c] via DPP fold16 in f32 (exact path). acc in AGPRs natively.
// ---------------------------------------------------------------------------
__global__ __launch_bounds__(256, 4) void k_proj(
    const float* __restrict__ x, const uint4* __restrict__ wfrag,
    __hip_bfloat16* __restrict__ featp, float* __restrict__ spp,
    float* __restrict__ pooledp)
{
    const int t    = threadIdx.x;
    const int lane = t & 63;
    const int wv   = t >> 6;
    const int blk  = blockIdx.x;         // b*16 + pxg
    const int b    = blk >> 4;
    const int pxg  = blk & 15;
    const int px0  = pxg * 64 + wv * 16;
    const int g    = lane >> 4;
    const int col  = lane & 15;
    const int px   = px0 + col;

    __shared__ float plds[C_][5];        // 10.2 KB pooled partials (pad 5)

    f32x4 acc0 = {0.f, 0.f, 0.f, 0.f};
    f32x4 acc1 = {0.f, 0.f, 0.f, 0.f};
    f32x4 acc2 = {0.f, 0.f, 0.f, 0.f};

    const float* xb = x + (size_t)b * C_ * HW_ + px;
    const uint4* wf = wfrag + lane;

    for (int ks = 0; ks < 16; ++ks) {
        const int c8 = ks * 32 + 8 * g;          // this lane's channel base
        const float* xc = xb + (size_t)c8 * HW_;

        float x0 = xc[0 * HW_], x1 = xc[1 * HW_], x2 = xc[2 * HW_],
              x3 = xc[3 * HW_], x4 = xc[4 * HW_], x5 = xc[5 * HW_],
              x6 = xc[6 * HW_], x7 = xc[7 * HW_];

        U8 a0, a1, a2, bu;
        a0.q = wf[(0 * 16 + ks) * 64];
        a1.q = wf[(1 * 16 + ks) * 64];
        a2.q = wf[(2 * 16 + ks) * 64];
        bu.s[0] = f2bf(x0); bu.s[1] = f2bf(x1);
        bu.s[2] = f2bf(x2); bu.s[3] = f2bf(x3);
        bu.s[4] = f2bf(x4); bu.s[5] = f2bf(x5);
        bu.s[6] = f2bf(x6); bu.s[7] = f2bf(x7);

        acc0 = __builtin_amdgcn_mfma_f32_16x16x32_bf16(a0.v, bu.v, acc0, 0, 0, 0);
        acc1 = __builtin_amdgcn_mfma_f32_16x16x32_bf16(a1.v, bu.v, acc1, 0, 0, 0);
        acc2 = __builtin_amdgcn_mfma_f32_16x16x32_bf16(a2.v, bu.v, acc2, 0, 0, 0);

        // pooled partials (f32): 16-px sum per channel, one write per row-group
        float s0 = dpp_fold16(x0), s1 = dpp_fold16(x1);
        float s2 = dpp_fold16(x2), s3 = dpp_fold16(x3);
        float s4 = dpp_fold16(x4), s5 = dpp_fold16(x5);
        float s6 = dpp_fold16(x6), s7 = dpp_fold16(x7);
        if (col == 0) {
            plds[c8 + 0][wv] = s0; plds[c8 + 1][wv] = s1;
            plds[c8 + 2][wv] = s2; plds[c8 + 3][wv] = s3;
            plds[c8 + 4][wv] = s4; plds[c8 + 5][wv] = s5;
            plds[c8 + 6][wv] = s6; plds[c8 + 7][wv] = s7;
        }
    }

    // spatial attention logit: acc2 row0 (= w_sp row) lives in lanes 0-15, reg x
    if (lane < 16) spp[(size_t)b * HW_ + px0 + lane] = acc2.x;

    // featp [b][n][r], r contiguous: lane writes r-quads g*4.. and 16+g*4..
    __hip_bfloat16* fb = featp + ((size_t)b * HW_ + px) * R_;
    ushort4 p0, p1;
    p0.x = f2bf(acc0.x); p0.y = f2bf(acc0.y);
    p0.z = f2bf(acc0.z); p0.w = f2bf(acc0.w);
    p1.x = f2bf(acc1.x); p1.y = f2bf(acc1.y);
    p1.z = f2bf(acc1.z); p1.w = f2bf(acc1.w);
    *(ushort4*)(fb + 4 * g)      = p0;
    *(ushort4*)(fb + 16 + 4 * g) = p1;

    __syncthreads();
    for (int c = t; c < C_; c += 256) {
        float s = plds[c][0] + plds[c][1] + plds[c][2] + plds[c][3];
        pooledp[((size_t)pxg * B_ + b) * C_ + c] = s;   // SUM over 64 px
    }
}

// ---------------------------------------------------------------------------
// B: per-batch block (64 blocks, 1024 threads = one per pixel).
// pooled from 16 px-group partials; mean[r] & fc1; channel attention; power
// iteration (col in regs, DPP fold8 + packed LDS partials); att -> min/max ->
// sigmoid; att_all = eigen * spatial. Structure proven in rounds 4-9.
// ---------------------------------------------------------------------------
__device__ __forceinline__ float dpp_fold8(float s) {
    int y;
    y = __builtin_amdgcn_update_dpp(0, __float_as_int(s), 0xB1, 0xF, 0xF, true);
    s += __int_as_float(y);
    y = __builtin_amdgcn_update_dpp(0, __float_as_int(s), 0x4E, 0xF, 0xF, true);
    s += __int_as_float(y);
    y = __builtin_amdgcn_update_dpp(0, __float_as_int(s), 0x141, 0xF, 0xF, true);
    s += __int_as_float(y);
    return s;
}

__global__ __launch_bounds__(1024) void k_eigen(
    const __hip_bfloat16* __restrict__ featp, const float* __restrict__ spp,
    const float* __restrict__ pooledp,
    const float* __restrict__ w_eig, const float* __restrict__ w_fc1,
    const float* __restrict__ b_fc1, const float* __restrict__ w_fc2,
    const float* __restrict__ b_fc2, const float* __restrict__ b_sp,
    const float* __restrict__ v0,
    float* __restrict__ ca_out, float* __restrict__ att_out)
{
    const int b    = blockIdx.x;
    const int t    = threadIdx.x;
    const int lane = t & 63;
    const int wave = t >> 6;

    __shared__ float pooledm[C_];
    __shared__ float meanv[R_], t1[R_], vv[R_], wred[R_];
    __shared__ float plds2[R_ / 2][128][2];   // 16 KB
    __shared__ float redmn[16], redmx[16], scal[2];

    // ---- pooled mean: combine the 16 pixel-group partials
    if (t < C_) {
        float s = 0.f;
#pragma unroll
        for (int pg = 0; pg < NPXG; ++pg)
            s += pooledp[((size_t)pg * B_ + b) * C_ + t];
        pooledm[t] = s * (1.f / 1024.f);
    }
    __syncthreads();

    // ---- mean[r] = (w_eig @ pooled_mean)[r]; t1[r] = relu(fc1 @ pm + b)
    if (t < 512) {
        const int r = t >> 4, k = t & 15;
        float pm = 0.f, pf = 0.f;
        for (int c = k; c < C_; c += 16) {
            float p = pooledm[c];
            pm = fmaf(w_eig[r * C_ + c], p, pm);
            pf = fmaf(w_fc1[r * C_ + c], p, pf);
        }
#pragma unroll
        for (int m = 8; m > 0; m >>= 1) {
            pm += __shfl_xor(pm, m, 64);
            pf += __shfl_xor(pf, m, 64);
        }
        if (k == 0) { meanv[r] = pm; t1[r] = fmaxf(pf + b_fc1[r], 0.f); }
    }
    __syncthreads();

    // ---- channel attention ca[c] = sigmoid(w_fc2[c,:] @ t1 + b_fc2[c])
    if (t < C_) {
        float s = b_fc2[t];
        const float4* w4 = (const float4*)(w_fc2 + (size_t)t * R_);
#pragma unroll
        for (int k = 0; k < 8; ++k) {
            float4 w = w4[k];
            s = fmaf(w.x, t1[4 * k + 0], s);
            s = fmaf(w.y, t1[4 * k + 1], s);
            s = fmaf(w.z, t1[4 * k + 2], s);
            s = fmaf(w.w, t1[4 * k + 3], s);
        }
        ca_out[b * C_ + t] = 1.f / (1.f + expf(-s));
    }

    // ---- centered column F_c[:, t] in registers (b_eig cancels)
    float col[R_];
    {
        union { __hip_bfloat16 h[R_]; uint4 qv[4]; } u;
        const uint4* src = (const uint4*)(featp + ((size_t)b * HW_ + t) * R_);
#pragma unroll
        for (int k = 0; k < 4; ++k) u.qv[k] = src[k];
#pragma unroll
        for (int r = 0; r < R_; ++r)
            col[r] = __bfloat162float(u.h[r]) - meanv[r];
    }

    // ---- v = v0 / ||v0||
    if (t < 64) {
        float vl = (t < R_) ? v0[b * R_ + t] : 0.f;
        float sq = vl * vl;
#pragma unroll
        for (int m = 32; m > 0; m >>= 1) sq += __shfl_xor(sq, m, 64);
        if (t < R_) vv[t] = vl / sqrtf(sq);
    }
    __syncthreads();

    // ---- 5 power iterations: v <- normalize(F (F^T v)/1023 + 1e-5 v)
    for (int it = 0; it < 5; ++it) {
        float uacc = 0.f;
#pragma unroll
        for (int r = 0; r < R_; ++r) uacc = fmaf(col[r], vv[r], uacc);
        uacc *= (1.f / 1023.f);

#pragma unroll
        for (int gg = 0; gg < R_ / 2; ++gg) {
            float s0 = dpp_fold8(col[2 * gg + 0] * uacc);
            float s1 = dpp_fold8(col[2 * gg + 1] * uacc);
            if ((t & 7) == 0) {
                plds2[gg][t >> 3][0] = s0;
                plds2[gg][t >> 3][1] = s1;
            }
        }
        __syncthreads();

        {
            const int r = t >> 5, i = t & 31;
            const int gg = r >> 1, e = r & 1;
            float s = plds2[gg][i][e] + plds2[gg][i + 32][e] +
                      plds2[gg][i + 64][e] + plds2[gg][i + 96][e];
#pragma unroll
            for (int m = 16; m > 0; m >>= 1) s += __shfl_xor(s, m, 64);
            if (i == 0) wred[r] = s;
        }
        __syncthreads();

        if (t < 64) {
            float w = (t < R_) ? wred[t] + 1e-5f * vv[t] : 0.f;
            float sq = w * w;
#pragma unroll
            for (int m = 32; m > 0; m >>= 1) sq += __shfl_xor(sq, m, 64);
            if (t < R_) vv[t] = w / (sqrtf(sq) + 1e-10f);
        }
        __syncthreads();
    }

    // ---- att, min/max, eigen_att, spatial_att
    float a = 0.f;
#pragma unroll
    for (int r = 0; r < R_; ++r) a = fmaf(col[r], vv[r], a);

    float mn = a, mx = a;
#pragma unroll
    for (int m = 32; m > 0; m >>= 1) {
        mn = fminf(mn, __shfl_xor(mn, m, 64));
        mx = fmaxf(mx, __shfl_xor(mx, m, 64));
    }
    if (lane == 0) { redmn[wave] = mn; redmx[wave] = mx; }
    __syncthreads();
    if (t == 0) {
        float m1 = redmn[0], m2 = redmx[0];
        for (int w = 1; w < 16; ++w) {
            m1 = fminf(m1, redmn[w]);
            m2 = fmaxf(m2, redmx[w]);
        }
        scal[0] = m1; scal[1] = m2;
    }
    __syncthreads();

    const float amin  = scal[0];
    const float denom = (scal[1] - scal[0]) + 1e-10f;
    float eig = 1.f / (1.f + expf(-((a - amin) / denom)));

    float spsig = 1.f / (1.f + expf(-(b_sp[0] + spp[(size_t)b * HW_ + t])));

    att_out[b * HW_ + t] = eig * spsig;
}

// ---------------------------------------------------------------------------
// C: out = x * (1 + ca[b,c] * att_all[b,n]), float4 streaming.
// ---------------------------------------------------------------------------
__global__ __launch_bounds__(256) void k_final(
    const float* __restrict__ x, const float* __restrict__ ca,
    const float* __restrict__ att, float* __restrict__ out)
{
    const int t   = threadIdx.x;
    const int blk = blockIdx.x;          // b*C_ + c
    const int b   = blk >> 9;
    const float cav  = ca[blk];
    const size_t base = (size_t)blk * HW_;

    float4 xv = ((const float4*)(x + base))[t];
    float4 av = ((const float4*)(att + (size_t)b * HW_))[t];
    float4 o;
    o.x = fmaf(xv.x * cav, av.x, xv.x);
    o.y = fmaf(xv.y * cav, av.y, xv.y);
    o.z = fmaf(xv.z * cav, av.z, xv.z);
    o.w = fmaf(xv.w * cav, av.w, xv.w);
    ((float4*)(out + base))[t] = o;
}

// ---------------------------------------------------------------------------
extern "C" void kernel_launch(void* const* d_in, const int* in_sizes, int n_in,
                              void* d_out, int out_size, void* d_ws, size_t ws_size,
                              hipStream_t stream) {
    const float* x     = (const float*)d_in[0];
    const float* w_fc1 = (const float*)d_in[1];
    const float* b_fc1 = (const float*)d_in[2];
    const float* w_fc2 = (const float*)d_in[3];
    const float* b_fc2 = (const float*)d_in[4];
    const float* w_eig = (const float*)d_in[5];
    // d_in[6] = b_eig: cancels under mean-centering; unused.
    const float* w_sp  = (const float*)d_in[7];
    const float* b_sp  = (const float*)d_in[8];
    const float* v0    = (const float*)d_in[9];
    float* out = (float*)d_out;

    // workspace layout (bytes); total ~7.0 MB (well under proven 18.4 MB)
    char* ws = (char*)d_ws;
    __hip_bfloat16* featp = (__hip_bfloat16*)ws;        // 4,194,304: 64*1024*32 bf16
    float* spp     = (float*)(ws + 4194304);            //   262,144: 64*1024 f32
    float* pooledp = (float*)(ws + 4456448);            // 2,097,152: 16*64*512 f32
    float* ca      = (float*)(ws + 6553600);            //   131,072: 64*512 f32
    float* att     = (float*)(ws + 6684672);            //   262,144: 64*1024 f32
    uint4* wfrag   = (uint4*)(ws + 6946816);            //    49,152: 3*16*64 uint4

    k_prep<<<12, 256, 0, stream>>>(w_eig, w_sp, wfrag);
    k_proj<<<B_ * NPXG, 256, 0, stream>>>(x, wfrag, featp, spp, pooledp);
    k_eigen<<<B_, 1024, 0, stream>>>(featp, spp, pooledp, w_eig, w_fc1, b_fc1,
                                     w_fc2, b_fc2, b_sp, v0, ca, att);
    k_final<<<B_ * C_, 256, 0, stream>>>(x, ca, att, out);
}